// Round 1
// baseline (721.754 us; speedup 1.0000x reference)
//
#include <hip/hip_runtime.h>

#define NN 100000
#define NE 3200000
#define NPART 391   // ceil(NN/256)
#define LN_EPS 1e-5f

// ---------------- CSR build ----------------

__global__ __launch_bounds__(256) void k_count(const int* __restrict__ dst, int* __restrict__ counts) {
  int e = blockIdx.x * 256 + threadIdx.x;
  if (e < NE) atomicAdd(&counts[dst[e]], 1);
}

__global__ __launch_bounds__(256) void k_nodeprep(const int* __restrict__ counts,
                                                  float* __restrict__ dinv_sqrt,
                                                  float* __restrict__ dinv) {
  int n = blockIdx.x * 256 + threadIdx.x;
  if (n < NN) {
    float d = (float)counts[n] + 1.0f;   // self-loop
    dinv_sqrt[n] = rsqrtf(d);
    dinv[n] = 1.0f / d;
  }
}

__global__ __launch_bounds__(256) void k_partial(const int* __restrict__ counts, int* __restrict__ partials) {
  int i = blockIdx.x * 256 + threadIdx.x;
  int v = (i < NN) ? counts[i] : 0;
  for (int o = 32; o > 0; o >>= 1) v += __shfl_xor(v, o);
  __shared__ int ws[4];
  if ((threadIdx.x & 63) == 0) ws[threadIdx.x >> 6] = v;
  __syncthreads();
  if (threadIdx.x == 0) partials[blockIdx.x] = ws[0] + ws[1] + ws[2] + ws[3];
}

__global__ __launch_bounds__(512) void k_root(int* __restrict__ partials) {
  int i = threadIdx.x;
  int v = (i < NPART) ? partials[i] : 0;
  int lane = i & 63, w = i >> 6;
  int x = v;
  for (int o = 1; o < 64; o <<= 1) {
    int t = __shfl_up(x, o);
    if (lane >= o) x += t;
  }
  __shared__ int ws[8];
  if (lane == 63) ws[w] = x;
  __syncthreads();
  int base = 0;
  for (int j = 0; j < w; ++j) base += ws[j];
  if (i < NPART) partials[i] = base + x - v;   // exclusive scan of block sums
}

__global__ __launch_bounds__(256) void k_scan_add(const int* __restrict__ counts, const int* __restrict__ partials,
                                                  int* __restrict__ offsets, int* __restrict__ cursor) {
  int i = blockIdx.x * 256 + threadIdx.x;
  int v = (i < NN) ? counts[i] : 0;
  int lane = threadIdx.x & 63, w = threadIdx.x >> 6;
  int x = v;
  for (int o = 1; o < 64; o <<= 1) {
    int t = __shfl_up(x, o);
    if (lane >= o) x += t;
  }
  __shared__ int ws[4];
  if (lane == 63) ws[w] = x;
  __syncthreads();
  int base = partials[blockIdx.x];
  for (int j = 0; j < w; ++j) base += ws[j];
  int excl = base + x - v;
  if (i < NN) { offsets[i] = excl; cursor[i] = excl; }
}

__global__ __launch_bounds__(256) void k_fill(const int* __restrict__ src, const int* __restrict__ dst,
                                              int* __restrict__ cursor, int* __restrict__ csr_src) {
  int e = blockIdx.x * 256 + threadIdx.x;
  if (e < NE) {
    int d = dst[e];
    int pos = atomicAdd(&cursor[d], 1);
    csr_src[pos] = src[e];
  }
}

// ---------------- GEMM1: xw1 = x @ W1  (128 -> 32) ----------------

__global__ __launch_bounds__(256) void k_gemm1(const float* __restrict__ x, const float* __restrict__ W1,
                                               float* __restrict__ xw1) {
  __shared__ float Wt[32][132];   // transposed, padded (4-way b128 conflicts = floor)
  __shared__ float xr[8][128];
  for (int idx = threadIdx.x; idx < 4096; idx += 256) {
    int k = idx >> 5, c = idx & 31;
    Wt[c][k] = W1[idx];
  }
  __syncthreads();
  int g = threadIdx.x >> 5, lane = threadIdx.x & 31;
  for (int tile = blockIdx.x; tile < NN / 8; tile += gridDim.x) {
    int row = tile * 8 + g;
    float4 xv = *(const float4*)&x[row * 128 + lane * 4];
    *(float4*)&xr[g][lane * 4] = xv;
    __syncthreads();
    float acc = 0.f;
    #pragma unroll
    for (int k4 = 0; k4 < 32; ++k4) {
      float4 a = *(const float4*)&xr[g][k4 * 4];
      float4 b = *(const float4*)&Wt[lane][k4 * 4];
      acc = fmaf(a.x, b.x, acc);
      acc = fmaf(a.y, b.y, acc);
      acc = fmaf(a.z, b.z, acc);
      acc = fmaf(a.w, b.w, acc);
    }
    xw1[row * 32 + lane] = acc;
    __syncthreads();
  }
}

// ------- fused: aggregate(xw) + self + bias -> LN -> ReLU -> @Wnext -------

template <int NOUT>
__global__ __launch_bounds__(256) void k_layer(const float* __restrict__ xw,
    const int* __restrict__ offsets, const int* __restrict__ counts, const int* __restrict__ csr_src,
    const float* __restrict__ dinv_sqrt, const float* __restrict__ dinv,
    const float* __restrict__ bias, const float* __restrict__ gam, const float* __restrict__ bet,
    const float* __restrict__ Wn, float* __restrict__ out) {
  __shared__ float Wl[1024];
  if (NOUT == 32) {
    for (int idx = threadIdx.x; idx < 1024; idx += 256) Wl[idx] = Wn[idx];
    __syncthreads();
  }
  int g = threadIdx.x >> 5, lane = threadIdx.x & 31;
  int n = blockIdx.x * 8 + g;      // grid is exact: NN/8 blocks
  int off = offsets[n], cnt = counts[n];
  float acc = 0.f;
  int i = 0;
  for (; i + 4 <= cnt; i += 4) {   // 4 independent gather chains for MLP
    int s0 = csr_src[off + i];
    int s1 = csr_src[off + i + 1];
    int s2 = csr_src[off + i + 2];
    int s3 = csr_src[off + i + 3];
    float c0 = dinv_sqrt[s0], c1 = dinv_sqrt[s1], c2 = dinv_sqrt[s2], c3 = dinv_sqrt[s3];
    float v0 = xw[s0 * 32 + lane], v1 = xw[s1 * 32 + lane];
    float v2 = xw[s2 * 32 + lane], v3 = xw[s3 * 32 + lane];
    acc = fmaf(c0, v0, acc);
    acc = fmaf(c1, v1, acc);
    acc = fmaf(c2, v2, acc);
    acc = fmaf(c3, v3, acc);
  }
  for (; i < cnt; ++i) {
    int s = csr_src[off + i];
    acc = fmaf(dinv_sqrt[s], xw[s * 32 + lane], acc);
  }
  float val = acc * dinv_sqrt[n] + xw[n * 32 + lane] * dinv[n] + bias[lane];
  // LayerNorm over the 32 channels held by this half-wave
  float sum = val;
  for (int o = 16; o > 0; o >>= 1) sum += __shfl_xor(sum, o, 32);
  float mu = sum * (1.f / 32.f);
  float d = val - mu;
  float sq = d * d;
  for (int o = 16; o > 0; o >>= 1) sq += __shfl_xor(sq, o, 32);
  float h = d * rsqrtf(sq * (1.f / 32.f) + LN_EPS) * gam[lane] + bet[lane];
  h = fmaxf(h, 0.f);   // ReLU (dropout = identity in eval)
  if (NOUT == 32) {
    float acc2 = 0.f;
    #pragma unroll
    for (int c = 0; c < 32; ++c) {
      float hc = __shfl(h, c, 32);
      acc2 = fmaf(hc, Wl[c * 32 + lane], acc2);
    }
    out[n * 32 + lane] = acc2;
  } else {
    float p0 = h * Wn[lane * 2];
    float p1 = h * Wn[lane * 2 + 1];
    for (int o = 16; o > 0; o >>= 1) { p0 += __shfl_xor(p0, o, 32); p1 += __shfl_xor(p1, o, 32); }
    if (lane == 0) { out[n * 2] = p0; out[n * 2 + 1] = p1; }
  }
}

// ---------------- final aggregation (2 channels) -> logits ----------------

__global__ __launch_bounds__(256) void k_final(const float* __restrict__ xw3,
    const int* __restrict__ offsets, const int* __restrict__ counts, const int* __restrict__ csr_src,
    const float* __restrict__ dinv_sqrt, const float* __restrict__ dinv,
    const float* __restrict__ b3, float* __restrict__ out) {
  int g = threadIdx.x >> 5, lane = threadIdx.x & 31;
  int n = blockIdx.x * 8 + g;
  int off = offsets[n], cnt = counts[n];
  float a0 = 0.f, a1 = 0.f;
  for (int i = lane; i < cnt; i += 32) {   // lanes stride edges, coalesced csr reads
    int s = csr_src[off + i];
    float cs = dinv_sqrt[s];
    float2 v = *(const float2*)&xw3[s * 2];
    a0 = fmaf(cs, v.x, a0);
    a1 = fmaf(cs, v.y, a1);
  }
  for (int o = 16; o > 0; o >>= 1) { a0 += __shfl_xor(a0, o, 32); a1 += __shfl_xor(a1, o, 32); }
  if (lane == 0) {
    float dsn = dinv_sqrt[n], dvn = dinv[n];
    float2 sv = *(const float2*)&xw3[n * 2];
    out[n * 2] = a0 * dsn + sv.x * dvn + b3[0];
    out[n * 2 + 1] = a1 * dsn + sv.y * dvn + b3[1];
  }
}

extern "C" void kernel_launch(void* const* d_in, const int* in_sizes, int n_in,
                              void* d_out, int out_size, void* d_ws, size_t ws_size,
                              hipStream_t stream) {
  (void)in_sizes; (void)n_in; (void)out_size; (void)ws_size;
  const float* x   = (const float*)d_in[0];
  const int*   ei  = (const int*)d_in[1];
  const float* W1  = (const float*)d_in[2];
  const float* b1  = (const float*)d_in[3];
  const float* g1  = (const float*)d_in[4];
  const float* be1 = (const float*)d_in[5];
  const float* W2  = (const float*)d_in[6];
  const float* b2  = (const float*)d_in[7];
  const float* g2  = (const float*)d_in[8];
  const float* be2 = (const float*)d_in[9];
  const float* W3  = (const float*)d_in[10];
  const float* b3  = (const float*)d_in[11];
  const int* src = ei;
  const int* dst = ei + NE;
  float* out = (float*)d_out;

  char* w = (char*)d_ws;
  int*   counts    = (int*)(w);
  int*   offsets   = (int*)(w + (512 << 10));
  int*   cursor    = (int*)(w + (1024 << 10));
  float* dinv_sqrt = (float*)(w + (1536 << 10));
  float* dinv      = (float*)(w + (2048 << 10));
  int*   partials  = (int*)(w + (2560 << 10));
  int*   csr_src   = (int*)(w + (3u << 20));    // 12.8 MB
  float* xw1       = (float*)(w + (16u << 20)); // 12.8 MB
  float* xw2       = (float*)(w + (29u << 20)); // 12.8 MB
  float* xw3       = (float*)(w + (42u << 20)); // 0.8 MB

  hipMemsetAsync(counts, 0, NN * sizeof(int), stream);
  k_count<<<NE / 256, 256, 0, stream>>>(dst, counts);
  k_nodeprep<<<NPART, 256, 0, stream>>>(counts, dinv_sqrt, dinv);
  k_partial<<<NPART, 256, 0, stream>>>(counts, partials);
  k_root<<<1, 512, 0, stream>>>(partials);
  k_scan_add<<<NPART, 256, 0, stream>>>(counts, partials, offsets, cursor);
  k_fill<<<NE / 256, 256, 0, stream>>>(src, dst, cursor, csr_src);
  k_gemm1<<<2048, 256, 0, stream>>>(x, W1, xw1);
  k_layer<32><<<NN / 8, 256, 0, stream>>>(xw1, offsets, counts, csr_src, dinv_sqrt, dinv, b1, g1, be1, W2, xw2);
  k_layer<2><<<NN / 8, 256, 0, stream>>>(xw2, offsets, counts, csr_src, dinv_sqrt, dinv, b2, g2, be2, W3, xw3);
  k_final<<<NN / 8, 256, 0, stream>>>(xw3, offsets, counts, csr_src, dinv_sqrt, dinv, b3, out);
}